// Round 12
// baseline (102.160 us; speedup 1.0000x reference)
//
#include <hip/hip_runtime.h>
#include <math.h>

#define CCH 4096
#define SP 891
#define NSL 32768

typedef __attribute__((ext_vector_type(8))) short short8;
typedef __attribute__((ext_vector_type(4))) float f32x4;

__device__ __forceinline__ unsigned int pack_bf2(float a, float b) {
  unsigned int ua = __builtin_bit_cast(unsigned int, a);
  unsigned int ub = __builtin_bit_cast(unsigned int, b);
  ua = (ua + 0x7fffu + ((ua >> 16) & 1u)) >> 16;
  ub = (ub + 0x7fffu + ((ub >> 16) & 1u)) >> 16;
  return ua | (ub << 16);
}

// ---------- setup: members + rowSid + cnt/off (80 blocks x 64) ----------
__global__ void k_setup(const int* __restrict__ im0, const int* __restrict__ im1,
                        int* cnt0, int* off0, int* cnt1, int* off1,
                        int* mem0, int* mem1, int* rs0, int* rs1) {
  int cb = blockIdx.x;
  int level = (cb >= 64) ? 1 : 0;
  int c = level ? cb - 64 : cb;
  const int* im = level ? im1 : im0;
  int* members = level ? mem1 : mem0;
  int* rs = level ? rs1 : rs0;
  int lane = threadIdx.x;  // 64
  int lt = 0;
  for (int ch = lane; ch < CCH; ch += 64) lt += (im[ch] < c) ? 1 : 0;
  for (int o = 32; o; o >>= 1) lt += __shfl_xor(lt, o, 64);
  int base = lt;
  int cnt = 0;
  for (int chunk = 0; chunk < CCH; chunk += 64) {
    int ch = chunk + lane;
    bool m = (im[ch] == c);
    unsigned long long mk = __ballot(m);
    int pos = __popcll(mk & ((1ull << lane) - 1ull));
    if (m) members[base + cnt + pos] = ch;
    cnt += __popcll(mk);
  }
  int n = cnt;
  if (lane == 0) {
    if (level) { cnt1[c] = n; off1[c] = base; }
    else       { cnt0[c] = n; off0[c] = base; }
  }
  __syncthreads();
  for (int r = lane; r < n; r += 64) {
    #pragma unroll
    for (int q = 0; q < 8; q++) {
      int p = 8 * r + q;
      int b = p / n, j = p - b * n;
      rs[(size_t)(base + r) * 8 + q] = b * CCH + members[base + j];
    }
  }
}

// ---------- pack rep slices into fragment-major bf16 tables (B operands) ----------
__global__ void k_brep(const float* __restrict__ X,
    const int* __restrict__ off0, const int* __restrict__ off1,
    const int* __restrict__ rs0, const int* __restrict__ rs1,
    uint4* __restrict__ Bfrag0, uint4* __restrict__ Bfrag1) {
  int gid = blockIdx.x * 4 + (threadIdx.x >> 6);  // 0..39
  int l = threadIdx.x & 63;
  int lrow = l & 15, hi = l >> 4;
  int level = (gid >= 32) ? 1 : 0;
  int q = level ? (gid - 32) : (gid >> 2);
  int ct = level ? 0 : (gid & 3);
  int cc = ct * 16 + lrow;
  int base = level ? off1[cc] : off0[cc];
  int sid = (level ? rs1 : rs0)[(size_t)base * 8 + q];
  const float* ap = X + (size_t)sid * SP + hi * 8;
  uint4* dst = (level ? Bfrag1 + (size_t)(q * 28) * 64
                      : Bfrag0 + (size_t)((q * 4 + ct) * 28) * 64) + l;
  #pragma unroll 3
  for (int kc = 0; kc < 27; kc++) {
    float4 fa0 = *(const float4*)(ap + kc * 32);
    float4 fa1 = *(const float4*)(ap + kc * 32 + 4);
    uint4 ua;
    ua.x = pack_bf2(fa0.x, fa0.y); ua.y = pack_bf2(fa0.z, fa0.w);
    ua.z = pack_bf2(fa1.x, fa1.y); ua.w = pack_bf2(fa1.z, fa1.w);
    dst[kc * 64] = ua;
  }
  {
    float4 fa0, fa1;
    if (hi == 3) {
      fa0 = make_float4(ap[864], ap[865], ap[866], 0.f);
      fa1 = make_float4(0.f, 0.f, 0.f, 0.f);
    } else {
      fa0 = *(const float4*)(ap + 864);
      fa1 = *(const float4*)(ap + 868);
    }
    uint4 ua;
    ua.x = pack_bf2(fa0.x, fa0.y); ua.y = pack_bf2(fa0.z, fa0.w);
    ua.z = pack_bf2(fa1.x, fa1.y); ua.w = pack_bf2(fa1.z, fa1.w);
    dst[27 * 64] = ua;
  }
}

// ---------- persistent pipelined GEMM: 512 blocks (all resident), q-loop with
// ---------- double-buffered LDS A-panel; loads for q+1 in flight during compute of q
__global__ __launch_bounds__(256) void k_gemm_all(const float* __restrict__ X,
    const int* __restrict__ rs0, const int* __restrict__ rs1,
    const uint4* __restrict__ Bfrag0, const uint4* __restrict__ Bfrag1,
    float* __restrict__ P8_0, float* __restrict__ P8_1, float* __restrict__ sn2) {
  __shared__ __align__(16) unsigned short T[2][16 * 904];  // 2 x 28.25 KB, 1808B rows
  __shared__ float4 Rf[256];                               // L1 reduce scratch
  const int tid = threadIdx.x;
  const int lev = blockIdx.x >> 8;
  const int rt = blockIdx.x & 255;
  const int* rs = lev ? rs1 : rs0;
  const int i = tid >> 4, j = tid & 15;
  const int l = tid & 63, w = tid >> 6;
  const int lrow = l & 15, hi = l >> 4;

  // register staging for one 16-row tile: 14 x float4 per thread (named)
  float4 s0a, s0b, s1a, s1b, s2a, s2b, s3a, s3b, s4a, s4b, s5a, s5b, s6a, s6b;
  int sidn;

#define ISSUE_ALL(qq) { \
    sidn = rs[(size_t)(rt * 16 + i) * 8 + (qq)]; \
    const float* sp_ = X + (size_t)sidn * SP; \
    s0a = *(const float4*)(sp_ + (0 * 16 + j) * 8); s0b = *(const float4*)(sp_ + (0 * 16 + j) * 8 + 4); \
    s1a = *(const float4*)(sp_ + (1 * 16 + j) * 8); s1b = *(const float4*)(sp_ + (1 * 16 + j) * 8 + 4); \
    s2a = *(const float4*)(sp_ + (2 * 16 + j) * 8); s2b = *(const float4*)(sp_ + (2 * 16 + j) * 8 + 4); \
    s3a = *(const float4*)(sp_ + (3 * 16 + j) * 8); s3b = *(const float4*)(sp_ + (3 * 16 + j) * 8 + 4); \
    s4a = *(const float4*)(sp_ + (4 * 16 + j) * 8); s4b = *(const float4*)(sp_ + (4 * 16 + j) * 8 + 4); \
    s5a = *(const float4*)(sp_ + (5 * 16 + j) * 8); s5b = *(const float4*)(sp_ + (5 * 16 + j) * 8 + 4); \
    if (j < 15) { s6a = *(const float4*)(sp_ + (6 * 16 + j) * 8); s6b = *(const float4*)(sp_ + (6 * 16 + j) * 8 + 4); } \
    else { s6a = make_float4(sp_[888], sp_[889], sp_[890], 0.f); s6b = make_float4(0.f, 0.f, 0.f, 0.f); } }

#define W1(Ti, kcc, va, vb) { \
    uint4 u_; \
    u_.x = pack_bf2(va.x, va.y); u_.y = pack_bf2(va.z, va.w); \
    u_.z = pack_bf2(vb.x, vb.y); u_.w = pack_bf2(vb.z, vb.w); \
    *(uint4*)((Ti) + ((kcc) * 16 + j) * 16) = u_; \
    s2l += va.x * va.x + va.y * va.y + va.z * va.z + va.w * va.w \
         + vb.x * vb.x + vb.y * vb.y + vb.z * vb.z + vb.w * vb.w; }

#define WRITE_ALL(buf) { \
    char* Ti = (char*)&T[(buf)][i * 904]; \
    float s2l = 0.f; \
    W1(Ti, 0, s0a, s0b) W1(Ti, 1, s1a, s1b) W1(Ti, 2, s2a, s2b) W1(Ti, 3, s3a, s3b) \
    W1(Ti, 4, s4a, s4b) W1(Ti, 5, s5a, s5b) W1(Ti, 6, s6a, s6b) \
    if (!lev) { \
      s2l += __shfl_xor(s2l, 1, 16); s2l += __shfl_xor(s2l, 2, 16); \
      s2l += __shfl_xor(s2l, 4, 16); s2l += __shfl_xor(s2l, 8, 16); \
      if (j == 0) sn2[sidn] = s2l; \
    } }

  auto computeL0 = [&](int qq, int buf) {
    const char* Abase = (const char*)&T[buf][0] + lrow * 1808;
    const uint4* bq = Bfrag0 + (size_t)((qq * 4 + w) * 28) * 64 + l;
    f32x4 acc = {0.f, 0.f, 0.f, 0.f};
    short8 A0 = *(const short8*)(Abase + (0 * 64 + hi * 16));
    short8 A1 = *(const short8*)(Abase + (1 * 64 + hi * 16));
    uint4 B0 = bq[0 * 64], B1 = bq[1 * 64], B2 = bq[2 * 64], B3 = bq[3 * 64];
    #pragma unroll
    for (int kc = 0; kc < 28; kc++) {
      short8 a = (kc & 1) ? A1 : A0;
      uint4 b = (kc & 3) == 0 ? B0 : (kc & 3) == 1 ? B1 : (kc & 3) == 2 ? B2 : B3;
      acc = __builtin_amdgcn_mfma_f32_16x16x32_bf16(a, __builtin_bit_cast(short8, b), acc, 0, 0, 0);
      if (kc + 2 < 28) {
        short8 an = *(const short8*)(Abase + ((kc + 2) * 64 + hi * 16));
        if (kc & 1) A1 = an; else A0 = an;
      }
      if (kc + 4 < 28) {
        uint4 bn = bq[(kc + 4) * 64];
        switch (kc & 3) { case 0: B0 = bn; break; case 1: B1 = bn; break;
                          case 2: B2 = bn; break; default: B3 = bn; }
      }
    }
    #pragma unroll
    for (int r = 0; r < 4; r++) {
      int row = rt * 16 + hi * 4 + r;
      P8_0[((size_t)qq * CCH + row) * 64 + w * 16 + lrow] = acc[r];
    }
  };

  auto computeL1 = [&](int qq, int buf) {
    const char* Abase = (const char*)&T[buf][0] + lrow * 1808;
    const uint4* bq = Bfrag1 + (size_t)(qq * 28) * 64 + l;
    f32x4 acc = {0.f, 0.f, 0.f, 0.f};
    #pragma unroll
    for (int kk = 0; kk < 7; kk++) {
      int kc = w * 7 + kk;
      short8 a = *(const short8*)(Abase + (kc * 64 + hi * 16));
      uint4 b = bq[kc * 64];
      acc = __builtin_amdgcn_mfma_f32_16x16x32_bf16(a, __builtin_bit_cast(short8, b), acc, 0, 0, 0);
    }
    __syncthreads();
    Rf[w * 64 + l] = make_float4(acc[0], acc[1], acc[2], acc[3]);
    __syncthreads();
    if (w == 0) {
      float4 v0 = Rf[l], v1 = Rf[64 + l], v2 = Rf[128 + l], v3 = Rf[192 + l];
      float vr[4] = { v0.x + v1.x + v2.x + v3.x, v0.y + v1.y + v2.y + v3.y,
                      v0.z + v1.z + v2.z + v3.z, v0.w + v1.w + v2.w + v3.w };
      #pragma unroll
      for (int r = 0; r < 4; r++) {
        int row = rt * 16 + hi * 4 + r;
        P8_1[((size_t)qq * CCH + row) * 16 + lrow] = vr[r];
      }
    }
  };

  // ---- pipeline: prologue stages tile q=0, loop overlaps load(q+1) with compute(q)
  ISSUE_ALL(0);
  WRITE_ALL(0);
  __syncthreads();
  for (int qq = 0; qq < 8; qq++) {
    const int buf = qq & 1;
    if (qq < 7) ISSUE_ALL(qq + 1);
    if (!lev) computeL0(qq, buf); else computeL1(qq, buf);
    if (qq < 7) {
      WRITE_ALL(buf ^ 1);
      __syncthreads();
    }
  }
#undef ISSUE_ALL
#undef W1
#undef WRITE_ALL
}

// ---------- per-cluster epilogue (512 threads), both levels in one dispatch ----------
template<int K>
__device__ __forceinline__ void fin_body(const float* __restrict__ P8,
    const float* __restrict__ sn2, const int* __restrict__ rs,
    const int* __restrict__ cnt, const int* __restrict__ off,
    double* __restrict__ clLoss, int c) {
  __shared__ float pcc[4096];
  __shared__ float red[512];
  __shared__ double redd[512];
  __shared__ float s_conc;
  const int n = cnt[c], base = off[c];
  const int tid = threadIdx.x;
  float rn0 = 0.f;
  #pragma unroll
  for (int qq = 0; qq < 8; qq++) rn0 += sn2[rs[(size_t)base * 8 + qq]];
  float t = 0.f;
  for (int r = tid; r < n; r += 512) {
    float pd = 0.f, rn = 0.f;
    #pragma unroll
    for (int qq = 0; qq < 8; qq++) {
      pd += P8[((size_t)qq * CCH + base + r) * K + c];
      rn += sn2[rs[(size_t)(base + r) * 8 + qq]];
    }
    pcc[r] = pd;
    if (r > 0) {
      float d2 = rn - 2.f * pd + rn0;
      t += (d2 > 0.f) ? sqrtf(d2) : 0.f;
    }
  }
  red[tid] = t; __syncthreads();
  for (int o = 256; o; o >>= 1) { if (tid < o) red[tid] += red[tid + o]; __syncthreads(); }
  if (tid == 0) s_conc = red[0] / ((float)n * logf((float)n + 10.f));
  __syncthreads();
  const float invc = 1.f / s_conc;
  const int wv = tid >> 6, lane = tid & 63;
  const int sub = (K == 64) ? 0 : (lane >> 4);
  const int cc = lane & (K - 1);
  constexpr int RPI = 8 * (64 / K);
  double acc = 0.0;
  for (int r = wv * (64 / K) + sub; r < n; r += RPI) {
    float s = 0.f;
    #pragma unroll
    for (int qq = 0; qq < 8; qq++) s += P8[((size_t)qq * CCH + base + r) * K + cc];
    float lg = s * invc;
    float m = lg;
    #pragma unroll
    for (int o = K / 2; o; o >>= 1) m = fmaxf(m, __shfl_xor(m, o, K));
    float e = expf(lg - m);
    float se = e;
    #pragma unroll
    for (int o = K / 2; o; o >>= 1) se += __shfl_xor(se, o, K);
    if (cc == 0) acc += (double)(m + logf(se)) - (double)(pcc[r] * invc);
  }
  redd[tid] = acc; __syncthreads();
  for (int o = 256; o; o >>= 1) { if (tid < o) redd[tid] += redd[tid + o]; __syncthreads(); }
  if (tid == 0) clLoss[c] = redd[0] / (double)n;
}

__global__ __launch_bounds__(512) void k_fin_all(const float* __restrict__ P8_0,
    const float* __restrict__ P8_1, const float* __restrict__ sn2,
    const int* __restrict__ rs0, const int* __restrict__ rs1,
    const int* __restrict__ cnt0, const int* __restrict__ off0,
    const int* __restrict__ cnt1, const int* __restrict__ off1,
    double* __restrict__ cl0, double* __restrict__ cl1) {
  if (blockIdx.x < 64) fin_body<64>(P8_0, sn2, rs0, cnt0, off0, cl0, blockIdx.x);
  else                 fin_body<16>(P8_1, sn2, rs1, cnt1, off1, cl1, blockIdx.x - 64);
}

// ---------- final scalars ----------
__global__ void k_final(const double* __restrict__ cl0, const double* __restrict__ cl1,
                        float* __restrict__ out) {
  if (threadIdx.x == 0) {
    double s0 = 0.0, s1 = 0.0;
    for (int i = 0; i < 64; i++) s0 += cl0[i];
    for (int i = 0; i < 16; i++) s1 += cl1[i];
    out[0] = (float)(s0 / 4096.0);
    out[1] = (float)(s1 / 8192.0);
  }
}

extern "C" void kernel_launch(void* const* d_in, const int* in_sizes, int n_in,
                              void* d_out, int out_size, void* d_ws, size_t ws_size,
                              hipStream_t stream) {
  const float* X = (const float*)d_in[0];
  const int* im0 = (const int*)d_in[1];
  const int* im1 = (const int*)d_in[2];
  float* out = (float*)d_out;

  char* w = (char*)d_ws;
  auto alloc = [&](size_t bytes) -> char* {
    char* p = w; w += (bytes + 255) & ~(size_t)255; return p;
  };
  int*    cnt0  = (int*)alloc(64 * 4);
  int*    off0  = (int*)alloc(64 * 4);
  int*    cnt1  = (int*)alloc(16 * 4);
  int*    off1  = (int*)alloc(16 * 4);
  int*    mem0  = (int*)alloc((size_t)CCH * 4);
  int*    mem1  = (int*)alloc((size_t)CCH * 4);
  int*    rs0   = (int*)alloc((size_t)CCH * 8 * 4);
  int*    rs1   = (int*)alloc((size_t)CCH * 8 * 4);
  float*  sn2   = (float*)alloc((size_t)NSL * 4);
  uint4*  Bfrag0 = (uint4*)alloc((size_t)32 * 28 * 64 * 16);
  uint4*  Bfrag1 = (uint4*)alloc((size_t)8 * 28 * 64 * 16);
  float*  P8_0  = (float*)alloc((size_t)8 * CCH * 64 * 4);
  float*  P8_1  = (float*)alloc((size_t)8 * CCH * 16 * 4);
  double* cl0   = (double*)alloc(64 * 8);
  double* cl1   = (double*)alloc(16 * 8);

  k_setup<<<80, 64, 0, stream>>>(im0, im1, cnt0, off0, cnt1, off1, mem0, mem1, rs0, rs1);
  k_brep<<<10, 256, 0, stream>>>(X, off0, off1, rs0, rs1, Bfrag0, Bfrag1);
  k_gemm_all<<<512, 256, 0, stream>>>(X, rs0, rs1, Bfrag0, Bfrag1, P8_0, P8_1, sn2);
  k_fin_all<<<80, 512, 0, stream>>>(P8_0, P8_1, sn2, rs0, rs1, cnt0, off0, cnt1, off1, cl0, cl1);
  k_final<<<1, 64, 0, stream>>>(cl0, cl1, out);
}